// Round 16
// baseline (1323.166 us; speedup 1.0000x reference)
//
#include <hip/hip_runtime.h>

// ---------------------------------------------------------------------------
// Grid attention v17, bf16 MFMA (gfx950). 4096 windows; n=49; D=512; 16h x 32.
// = v12 (709us champion) + (1) MERGED projection loop: Q,K,V computed in one
//   16-iter loop -- 8 ldXY feed 12 MFMAs/iter (v12: two serial passes at 4 and
//   8 MFMAs per 4 reads); 3 weight streams rolling 8-deep (~200 VGPR, fits
//   2 waves/SIMD). (2) s_setprio(1) around MFMA clusters (T5; the 2 waves/SIMD
//   are from different pairs -> phase diversity -> setprio pays).
// LDS = 141824: xb 50176 | yb 50176 | 4 pairs x 10368 (qb 3136|kb 3136|vt 4096)
// ws (2.5MB): Wq/Wk/Wv pre-swizzled B-frags + bias (sim^T layout).
// ---------------------------------------------------------------------------

typedef __bf16 bf16x8 __attribute__((ext_vector_type(8)));
typedef __attribute__((ext_vector_type(4))) float f32x4;

#define DEVI __device__ __forceinline__

DEVI unsigned short f2bf(float f) {  // round-to-nearest-even
  union { float f; unsigned u; } v; v.f = f;
  unsigned r = v.u + 0x7FFFu + ((v.u >> 16) & 1u);
  return (unsigned short)(r >> 16);
}
DEVI unsigned pkbf(float a, float b) {
  return (unsigned)f2bf(a) | ((unsigned)f2bf(b) << 16);
}

#define MFMA16(a, b, c) __builtin_amdgcn_mfma_f32_16x16x32_bf16((a), (b), (c), 0, 0, 0)

#define SWZ_Y(r)  ((((unsigned)(r)) & 7u) << 4)
#define SWZ_A(r)  (((((unsigned)(r)) >> 2) & 3u) << 5)
#define SWZ_P(r)  ((((unsigned)(r)) & 7u) << 4)
#define SWZ_VT(r) ((((unsigned)(r)) & 7u) << 4)

// ---------------- prep: weights -> swizzled bf16 frags, bias -> sim^T layout
__global__ void prep_kernel(const float* __restrict__ Wq, const float* __restrict__ Wkv,
                            const float* __restrict__ bt, char* __restrict__ ws) {
  int t = blockIdx.x * 256 + threadIdx.x;
  if (t < 786432) {  // 3 * 16 * 2 * 16 * 64 * 8 bf16 elements
    int e = t & 7, lane = (t >> 3) & 63, ks = (t >> 9) & 15, nt = (t >> 13) & 1,
        h = (t >> 14) & 15, T = t >> 18;
    int row = ks * 32 + (lane >> 4) * 8 + e;     // K index in [0,512)
    int col = h * 32 + nt * 16 + (lane & 15);    // N index
    float v;
    if (T == 0)      v = Wq[row * 512 + col] * 0.17677669529663687f;  // fold 1/sqrt(32)
    else if (T == 1) v = Wkv[row * 1024 + col];
    else             v = Wkv[row * 1024 + 512 + col];
    ((unsigned short*)ws)[t] = f2bf(v);
  }
  if (t < 262144) {  // 16h * 4 i-tile * 4 j-tile * 64 lane * 4 reg, sim^T layout
    int r = t & 3, lane = (t >> 2) & 63, jt = (t >> 8) & 3, it = (t >> 10) & 3,
        h = (t >> 12) & 15;
    int i = it * 16 + (lane & 15);               // query: lane&15 = col of sim^T
    int j = jt * 16 + ((lane >> 4) & 3) * 4 + r; // key: regs = rows of sim^T
    float v;
    if (j >= 49)      v = -1e30f;   // mask padded key slots
    else if (i >= 49) v = 0.0f;     // padded query cols: keep finite
    else {
      int hi = i / 7, wi = i % 7, hj = j / 7, wj = j % 7;
      v = bt[((hi - hj + 6) * 13 + (wi - wj + 6)) * 16 + h];
    }
    ((float*)(ws + 1572864))[t] = v;
  }
}

// ---------------- LDS fragment loaders --------------------------------------
DEVI bf16x8 ldXY(const char* base, int row, int kc) {
  unsigned a = ((unsigned)(row * 1024 + kc * 2)) ^ SWZ_Y(row);
  return *(const bf16x8*)(base + a);
}
DEVI bf16x8 ldXY_c(const char* base, int row, int kc) {
  int rc = row < 48 ? row : 48;
  bf16x8 v = ldXY(base, rc, kc);
  if (row > 48) {
    union { long long z[2]; bf16x8 v; } u; u.z[0] = 0; u.z[1] = 0;
    v = u.v;
  }
  return v;
}
DEVI bf16x8 ldQK(const char* base, int row, int kc) {
  int rc = row < 48 ? row : 48;
  unsigned a = ((unsigned)(rc * 64 + kc * 2)) ^ SWZ_A(rc);
  return *(const bf16x8*)(base + a);
}
DEVI bf16x8 ldP2(const char* base, int row, int jc) {
  int rc = row < 48 ? row : 48;
  unsigned a = ((unsigned)(rc * 128 + jc * 2)) ^ SWZ_P(rc);
  return *(const bf16x8*)(base + a);
}
DEVI bf16x8 ldVT(const char* base, int dh, int jc) {
  unsigned a = ((unsigned)(dh * 128 + jc * 2)) ^ SWZ_VT(dh);
  return *(const bf16x8*)(base + a);
}

// ---------------- main fused kernel ----------------------------------------
__global__ __launch_bounds__(512, 2)
void attn_kernel(const float* __restrict__ x, const float* __restrict__ y,
                 const char* __restrict__ wsW, const float* __restrict__ biasD,
                 float* __restrict__ out) {
  extern __shared__ char smem[];
  char* xb = smem;            // 50176
  char* yb = smem + 50176;    // 50176
  const int tid = threadIdx.x;
  const int lane = tid & 63, wave = tid >> 6;
  const int p = wave >> 1, sub = wave & 1;
  const int g = lane >> 4, lr = lane & 15;
  char* pbase = smem + 100352 + p * 10368;  // per-PAIR scratch
  char* qb = pbase;             // 3136
  char* kb = pbase + 3136;      // 3136
  char* vt = pbase + 6272;      // 4096
  char* Pb = pbase;             // P aliases qb+kb (6272B) -- barrier-guarded

  const int bw = blockIdx.x;
  const float* xs = x + (size_t)bw * 25088;
  const float* ys = y + (size_t)bw * 25088;

  // ---- stage x,y windows to LDS as bf16 ----
  for (int it = tid; it < 6272; it += 512) {
    float4 v = ((const float4*)xs)[it];
    float4 w = ((const float4*)ys)[it];
    int i = it >> 7;               // row 0..48
    int k = (it & 127) << 2;       // col 0..508
    unsigned a = ((unsigned)(i * 1024 + k * 2)) ^ SWZ_Y(i);
    uint2 ux, uy;
    ux.x = pkbf(v.x, v.y); ux.y = pkbf(v.z, v.w);
    uy.x = pkbf(w.x, w.y); uy.y = pkbf(w.z, w.w);
    *(uint2*)(xb + a) = ux;
    *(uint2*)(yb + a) = uy;
  }

  const bf16x8* wsQ = (const bf16x8*)wsW;
  const bf16x8* wsK = (const bf16x8*)(wsW + 524288);
  const bf16x8* wsV = (const bf16x8*)(wsW + 1048576);
  const f32x4* bD = (const f32x4*)biasD;
  const f32x4 fz = {0.f, 0.f, 0.f, 0.f};

  for (int hi = 0; hi < 4; ++hi) {
    const int h = p * 4 + hi;

    __syncthreads();  // scratch free: partner's attn reads of prev head done

    // ---- MERGED projection: Q,K,V in one loop; 3 streams 8-deep ----
    f32x4 accq[4], acck[4], accv[4];
    #pragma unroll
    for (int mt = 0; mt < 4; ++mt) { accq[mt] = fz; acck[mt] = fz; accv[mt] = fz; }
    {
      const bf16x8* pQ = wsQ + (size_t)((h * 2 + sub) * 16) * 64 + lane;
      const bf16x8* pK = wsK + (size_t)((h * 2 + sub) * 16) * 64 + lane;
      const bf16x8* pV = wsV + (size_t)((h * 2 + sub) * 16) * 64 + lane;
      bf16x8 qsr[8], ksr[8], vsr[8];
      #pragma unroll
      for (int i = 0; i < 8; ++i) {
        qsr[i] = pQ[i * 64]; ksr[i] = pK[i * 64]; vsr[i] = pV[i * 64];
      }
      #pragma unroll
      for (int ks = 0; ks < 16; ++ks) {
        bf16x8 bq = qsr[ks & 7], bk = ksr[ks & 7], bv = vsr[ks & 7];
        if (ks < 8) {
          qsr[ks & 7] = pQ[(ks + 8) * 64];
          ksr[ks & 7] = pK[(ks + 8) * 64];
          vsr[ks & 7] = pV[(ks + 8) * 64];
        }
        int kc = ks * 32 + g * 8;
        bf16x8 xa0 = ldXY(xb, lr, kc);
        bf16x8 xa1 = ldXY(xb, lr + 16, kc);
        bf16x8 xa2 = ldXY(xb, lr + 32, kc);
        bf16x8 xa3 = ldXY_c(xb, lr + 48, kc);
        bf16x8 ya0 = ldXY(yb, lr, kc);
        bf16x8 ya1 = ldXY(yb, lr + 16, kc);
        bf16x8 ya2 = ldXY(yb, lr + 32, kc);
        bf16x8 ya3 = ldXY_c(yb, lr + 48, kc);
        __builtin_amdgcn_s_setprio(1);
        accq[0] = MFMA16(xa0, bq, accq[0]);
        accq[1] = MFMA16(xa1, bq, accq[1]);
        accq[2] = MFMA16(xa2, bq, accq[2]);
        accq[3] = MFMA16(xa3, bq, accq[3]);
        acck[0] = MFMA16(ya0, bk, acck[0]);
        acck[1] = MFMA16(ya1, bk, acck[1]);
        acck[2] = MFMA16(ya2, bk, acck[2]);
        acck[3] = MFMA16(ya3, bk, acck[3]);
        accv[0] = MFMA16(ya0, bv, accv[0]);
        accv[1] = MFMA16(ya1, bv, accv[1]);
        accv[2] = MFMA16(ya2, bv, accv[2]);
        accv[3] = MFMA16(ya3, bv, accv[3]);
        __builtin_amdgcn_s_setprio(0);
      }
    }
    // store q,k (u16 scatter, conflict-free swz) and vt (packed uint2)
    #pragma unroll
    for (int mt = 0; mt < 4; ++mt) {
      #pragma unroll
      for (int r = 0; r < 4; ++r) {
        int row = mt * 16 + g * 4 + r;
        if (row < 49) {
          unsigned a = ((unsigned)(row * 64 + (sub * 16 + lr) * 2)) ^ SWZ_A(row);
          *(unsigned short*)(qb + a) = f2bf(accq[mt][r]);
          *(unsigned short*)(kb + a) = f2bf(acck[mt][r]);
        }
      }
      int dh = sub * 16 + lr;
      int t0 = mt * 16 + g * 4;
      unsigned a = ((unsigned)(dh * 128 + t0 * 2)) ^ SWZ_VT(dh);
      uint2 pk;
      pk.x = pkbf(accv[mt][0], accv[mt][1]);
      pk.y = pkbf(accv[mt][2], accv[mt][3]);
      *(uint2*)(vt + a) = pk;
    }

    __syncthreads();  // q,k,vt visible to both waves of the pair

    // ======== attention (swapped QK^T; one alias-guard barrier) ========
    f32x4 bias[2][4];
    #pragma unroll
    for (int mi = 0; mi < 2; ++mi)
      #pragma unroll
      for (int jt = 0; jt < 4; ++jt)
        bias[mi][jt] = bD[(size_t)(((h * 4 + sub * 2 + mi) * 4 + jt) * 64 + lane)];

    // sim^T = MFMA(A=k, B=q): col = query i (lane&15), regs = key j
    bf16x8 qa[2], kf[4];
    #pragma unroll
    for (int mi = 0; mi < 2; ++mi) qa[mi] = ldQK(qb, sub * 32 + mi * 16 + lr, g * 8);
    #pragma unroll
    for (int jt = 0; jt < 4; ++jt) kf[jt] = ldQK(kb, jt * 16 + lr, g * 8);
    f32x4 accs[2][4];
    __builtin_amdgcn_s_setprio(1);
    #pragma unroll
    for (int mi = 0; mi < 2; ++mi)
      #pragma unroll
      for (int jt = 0; jt < 4; ++jt)
        accs[mi][jt] = MFMA16(kf[jt], qa[mi], fz);
    __builtin_amdgcn_s_setprio(0);

    // in-lane softmax (16 j-values/lane) + 2 shfl across g-replicas; normalize
    uint2 pks[2][4];
    #pragma unroll
    for (int mi = 0; mi < 2; ++mi) {
      f32x4 vals[4];
      #pragma unroll
      for (int jt = 0; jt < 4; ++jt) vals[jt] = accs[mi][jt] + bias[mi][jt];
      float m = vals[0][0];
      #pragma unroll
      for (int jt = 0; jt < 4; ++jt)
        #pragma unroll
        for (int r = 0; r < 4; ++r) m = fmaxf(m, vals[jt][r]);
      m = fmaxf(m, __shfl_xor(m, 16));
      m = fmaxf(m, __shfl_xor(m, 32));
      float s = 0.f;
      #pragma unroll
      for (int jt = 0; jt < 4; ++jt)
        #pragma unroll
        for (int r = 0; r < 4; ++r) {
          float pv = __expf(vals[jt][r] - m);
          vals[jt][r] = pv;
          s += pv;
        }
      s += __shfl_xor(s, 16);
      s += __shfl_xor(s, 32);
      float inv = 1.0f / s;
      #pragma unroll
      for (int jt = 0; jt < 4; ++jt) {
        pks[mi][jt].x = pkbf(vals[jt][0] * inv, vals[jt][1] * inv);
        pks[mi][jt].y = pkbf(vals[jt][2] * inv, vals[jt][3] * inv);
      }
    }

    __syncthreads();  // both waves done reading q/k -> P may overwrite alias

    // P write: packed uint2, own rows, conflict-free
    #pragma unroll
    for (int mi = 0; mi < 2; ++mi) {
      int i = sub * 32 + mi * 16 + lr;
      if (i < 49) {
        #pragma unroll
        for (int jt = 0; jt < 4; ++jt) {
          unsigned a = ((unsigned)(i * 128 + (jt * 16 + g * 4) * 2)) ^ SWZ_P(i);
          *(uint2*)(Pb + a) = pks[mi][jt];
        }
      }
    }

    // PV: out^T[dh][i] = V^T @ P^T ; A = vt rows (pair-shared), B = own P rows
    f32x4 acco[2][2];
    acco[0][0] = fz; acco[0][1] = fz; acco[1][0] = fz; acco[1][1] = fz;
    #pragma unroll
    for (int ks = 0; ks < 2; ++ks) {
      int jc = ks * 32 + g * 8;
      bf16x8 av0 = ldVT(vt, lr, jc);
      bf16x8 av1 = ldVT(vt, lr + 16, jc);
      bf16x8 bp0 = ldP2(Pb, sub * 32 + lr, jc);
      bf16x8 bp1 = ldP2(Pb, sub * 32 + 16 + lr, jc);
      __builtin_amdgcn_s_setprio(1);
      acco[0][0] = MFMA16(av0, bp0, acco[0][0]);
      acco[0][1] = MFMA16(av0, bp1, acco[0][1]);
      acco[1][0] = MFMA16(av1, bp0, acco[1][0]);
      acco[1][1] = MFMA16(av1, bp1, acco[1][1]);
      __builtin_amdgcn_s_setprio(0);
    }

    // store (already normalized): tok = col (lane&15), dh rows f32x4
    float* ow = out + (size_t)bw * 25088 + h * 32;
    #pragma unroll
    for (int it = 0; it < 2; ++it) {
      int tok = sub * 32 + it * 16 + lr;
      if (tok < 49) {
        #pragma unroll
        for (int md = 0; md < 2; ++md)
          *(f32x4*)(&ow[(size_t)tok * 512 + md * 16 + g * 4]) = acco[md][it];
      }
    }
  }
}

extern "C" void kernel_launch(void* const* d_in, const int* in_sizes, int n_in,
                              void* d_out, int out_size, void* d_ws, size_t ws_size,
                              hipStream_t stream) {
  (void)in_sizes; (void)n_in; (void)out_size; (void)ws_size;
  const float* x = (const float*)d_in[0];
  const float* y = (const float*)d_in[1];
  const float* Wq = (const float*)d_in[2];
  const float* Wkv = (const float*)d_in[3];
  const float* bt = (const float*)d_in[4];
  float* out = (float*)d_out;
  char* ws = (char*)d_ws;

  prep_kernel<<<3072, 256, 0, stream>>>(Wq, Wkv, bt, ws);

  (void)hipFuncSetAttribute((const void*)attn_kernel,
                            hipFuncAttributeMaxDynamicSharedMemorySize, 141824);
  attn_kernel<<<4096, 512, 141824, stream>>>(x, y, (const char*)ws,
                                             (const float*)(ws + 1572864), out);
}

// Round 17
// 977.499 us; speedup vs baseline: 1.3536x; 1.3536x over previous
//
#include <hip/hip_runtime.h>

// ---------------------------------------------------------------------------
// Grid attention v18, bf16 MFMA (gfx950). 4096 windows; n=49; D=512; 16h x 32.
// = v12 (709us champion) with projections M-SPLIT (wave owns token rows
//   sub*32..+31 x ALL 32 dh cols): each LDS A-frag read feeds 2 (Q) / 4 (KV)
//   MFMAs vs v12's 1 / 2 -- proj A-reads halve (128->64 b128 per wave-head;
//   LDS pipe was ~71% of block time). Weight streams: Q 2x8-deep, KV 4x4-deep
//   -- both exactly 64 VGPR, same budget as v12 (no spill).
// Attention (swapped QK^T, in-lane softmax, packed P) byte-identical to v12.
// LDS = 141824: xb 50176 | yb 50176 | 4 pairs x 10368 (qb 3136|kb 3136|vt 4096)
// ws (2.5MB): Wq/Wk/Wv pre-swizzled B-frags + bias (sim^T layout).
// ---------------------------------------------------------------------------

typedef __bf16 bf16x8 __attribute__((ext_vector_type(8)));
typedef __attribute__((ext_vector_type(4))) float f32x4;

#define DEVI __device__ __forceinline__

DEVI unsigned short f2bf(float f) {  // round-to-nearest-even
  union { float f; unsigned u; } v; v.f = f;
  unsigned r = v.u + 0x7FFFu + ((v.u >> 16) & 1u);
  return (unsigned short)(r >> 16);
}
DEVI unsigned pkbf(float a, float b) {
  return (unsigned)f2bf(a) | ((unsigned)f2bf(b) << 16);
}

#define MFMA16(a, b, c) __builtin_amdgcn_mfma_f32_16x16x32_bf16((a), (b), (c), 0, 0, 0)

#define SWZ_Y(r)  ((((unsigned)(r)) & 7u) << 4)
#define SWZ_A(r)  (((((unsigned)(r)) >> 2) & 3u) << 5)
#define SWZ_P(r)  ((((unsigned)(r)) & 7u) << 4)
#define SWZ_VT(r) ((((unsigned)(r)) & 7u) << 4)

// ---------------- prep: weights -> swizzled bf16 frags, bias -> sim^T layout
__global__ void prep_kernel(const float* __restrict__ Wq, const float* __restrict__ Wkv,
                            const float* __restrict__ bt, char* __restrict__ ws) {
  int t = blockIdx.x * 256 + threadIdx.x;
  if (t < 786432) {  // 3 * 16 * 2 * 16 * 64 * 8 bf16 elements
    int e = t & 7, lane = (t >> 3) & 63, ks = (t >> 9) & 15, nt = (t >> 13) & 1,
        h = (t >> 14) & 15, T = t >> 18;
    int row = ks * 32 + (lane >> 4) * 8 + e;     // K index in [0,512)
    int col = h * 32 + nt * 16 + (lane & 15);    // N index
    float v;
    if (T == 0)      v = Wq[row * 512 + col] * 0.17677669529663687f;  // fold 1/sqrt(32)
    else if (T == 1) v = Wkv[row * 1024 + col];
    else             v = Wkv[row * 1024 + 512 + col];
    ((unsigned short*)ws)[t] = f2bf(v);
  }
  if (t < 262144) {  // 16h * 4 i-tile * 4 j-tile * 64 lane * 4 reg, sim^T layout
    int r = t & 3, lane = (t >> 2) & 63, jt = (t >> 8) & 3, it = (t >> 10) & 3,
        h = (t >> 12) & 15;
    int i = it * 16 + (lane & 15);               // query: lane&15 = col of sim^T
    int j = jt * 16 + ((lane >> 4) & 3) * 4 + r; // key: regs = rows of sim^T
    float v;
    if (j >= 49)      v = -1e30f;   // mask padded key slots
    else if (i >= 49) v = 0.0f;     // padded query cols: keep finite
    else {
      int hi = i / 7, wi = i % 7, hj = j / 7, wj = j % 7;
      v = bt[((hi - hj + 6) * 13 + (wi - wj + 6)) * 16 + h];
    }
    ((float*)(ws + 1572864))[t] = v;
  }
}

// ---------------- LDS fragment loaders --------------------------------------
DEVI bf16x8 ldXY(const char* base, int row, int kc) {
  unsigned a = ((unsigned)(row * 1024 + kc * 2)) ^ SWZ_Y(row);
  return *(const bf16x8*)(base + a);
}
DEVI bf16x8 ldXY_c(const char* base, int row, int kc) {
  int rc = row < 48 ? row : 48;
  bf16x8 v = ldXY(base, rc, kc);
  if (row > 48) {
    union { long long z[2]; bf16x8 v; } u; u.z[0] = 0; u.z[1] = 0;
    v = u.v;
  }
  return v;
}
DEVI bf16x8 ldQK(const char* base, int row, int kc) {
  int rc = row < 48 ? row : 48;
  unsigned a = ((unsigned)(rc * 64 + kc * 2)) ^ SWZ_A(rc);
  return *(const bf16x8*)(base + a);
}
DEVI bf16x8 ldP2(const char* base, int row, int jc) {
  int rc = row < 48 ? row : 48;
  unsigned a = ((unsigned)(rc * 128 + jc * 2)) ^ SWZ_P(rc);
  return *(const bf16x8*)(base + a);
}
DEVI bf16x8 ldVT(const char* base, int dh, int jc) {
  unsigned a = ((unsigned)(dh * 128 + jc * 2)) ^ SWZ_VT(dh);
  return *(const bf16x8*)(base + a);
}

// ---------------- main fused kernel ----------------------------------------
__global__ __launch_bounds__(512, 2)
void attn_kernel(const float* __restrict__ x, const float* __restrict__ y,
                 const char* __restrict__ wsW, const float* __restrict__ biasD,
                 float* __restrict__ out) {
  extern __shared__ char smem[];
  char* xb = smem;            // 50176
  char* yb = smem + 50176;    // 50176
  const int tid = threadIdx.x;
  const int lane = tid & 63, wave = tid >> 6;
  const int p = wave >> 1, sub = wave & 1;
  const int g = lane >> 4, lr = lane & 15;
  char* pbase = smem + 100352 + p * 10368;  // per-PAIR scratch
  char* qb = pbase;             // 3136
  char* kb = pbase + 3136;      // 3136
  char* vt = pbase + 6272;      // 4096
  char* Pb = pbase;             // P aliases qb+kb (6272B) -- barrier-guarded

  const int bw = blockIdx.x;
  const float* xs = x + (size_t)bw * 25088;
  const float* ys = y + (size_t)bw * 25088;

  // ---- stage x,y windows to LDS as bf16 ----
  for (int it = tid; it < 6272; it += 512) {
    float4 v = ((const float4*)xs)[it];
    float4 w = ((const float4*)ys)[it];
    int i = it >> 7;               // row 0..48
    int k = (it & 127) << 2;       // col 0..508
    unsigned a = ((unsigned)(i * 1024 + k * 2)) ^ SWZ_Y(i);
    uint2 ux, uy;
    ux.x = pkbf(v.x, v.y); ux.y = pkbf(v.z, v.w);
    uy.x = pkbf(w.x, w.y); uy.y = pkbf(w.z, w.w);
    *(uint2*)(xb + a) = ux;
    *(uint2*)(yb + a) = uy;
  }

  const bf16x8* wsQ = (const bf16x8*)wsW;
  const bf16x8* wsK = (const bf16x8*)(wsW + 524288);
  const bf16x8* wsV = (const bf16x8*)(wsW + 1048576);
  const f32x4* bD = (const f32x4*)biasD;
  const f32x4 fz = {0.f, 0.f, 0.f, 0.f};

  // M-split proj rows: this wave owns token rows sub*32..+31
  const int ar0 = sub * 32 + lr;        // always <= 47
  const int ar1 = sub * 32 + 16 + lr;   // 48..63 when sub=1 -> clamp

  for (int hi = 0; hi < 4; ++hi) {
    const int h = p * 4 + hi;

    __syncthreads();  // scratch free: partner's attn reads of prev head done

    // ---- Q-pass, M-split: rows sub*32..+31 x cols 0..31; 2 streams 8-deep --
    f32x4 accq[2][2];  // [mt][nt]
    accq[0][0] = fz; accq[0][1] = fz; accq[1][0] = fz; accq[1][1] = fz;
    {
      const bf16x8* pQ0 = wsQ + (size_t)((h * 2 + 0) * 16) * 64 + lane;
      const bf16x8* pQ1 = wsQ + (size_t)((h * 2 + 1) * 16) * 64 + lane;
      bf16x8 q0r[8], q1r[8];
      #pragma unroll
      for (int i = 0; i < 8; ++i) { q0r[i] = pQ0[i * 64]; q1r[i] = pQ1[i * 64]; }
      #pragma unroll
      for (int ks = 0; ks < 16; ++ks) {
        bf16x8 bq0 = q0r[ks & 7], bq1 = q1r[ks & 7];
        if (ks < 8) {
          q0r[ks & 7] = pQ0[(ks + 8) * 64];
          q1r[ks & 7] = pQ1[(ks + 8) * 64];
        }
        int kc = ks * 32 + g * 8;
        bf16x8 xa0 = ldXY(xb, ar0, kc);
        bf16x8 xa1 = ldXY_c(xb, ar1, kc);
        accq[0][0] = MFMA16(xa0, bq0, accq[0][0]);
        accq[1][0] = MFMA16(xa1, bq0, accq[1][0]);
        accq[0][1] = MFMA16(xa0, bq1, accq[0][1]);
        accq[1][1] = MFMA16(xa1, bq1, accq[1][1]);
      }
    }
    // store q: [row][dh] u16 scatter (rows sub*32.., both col-halves)
    #pragma unroll
    for (int mt = 0; mt < 2; ++mt)
      #pragma unroll
      for (int nt = 0; nt < 2; ++nt)
        #pragma unroll
        for (int r = 0; r < 4; ++r) {
          int row = sub * 32 + mt * 16 + g * 4 + r;
          if (row < 49) {
            unsigned a = ((unsigned)(row * 64 + (nt * 16 + lr) * 2)) ^ SWZ_A(row);
            *(unsigned short*)(qb + a) = f2bf(accq[mt][nt][r]);
          }
        }

    // ---- KV-pass, M-split: 4 streams 4-deep (k0,k1,v0,v1) ----
    f32x4 acck[2][2], accv[2][2];
    acck[0][0] = fz; acck[0][1] = fz; acck[1][0] = fz; acck[1][1] = fz;
    accv[0][0] = fz; accv[0][1] = fz; accv[1][0] = fz; accv[1][1] = fz;
    {
      const bf16x8* pK0 = wsK + (size_t)((h * 2 + 0) * 16) * 64 + lane;
      const bf16x8* pK1 = wsK + (size_t)((h * 2 + 1) * 16) * 64 + lane;
      const bf16x8* pV0 = wsV + (size_t)((h * 2 + 0) * 16) * 64 + lane;
      const bf16x8* pV1 = wsV + (size_t)((h * 2 + 1) * 16) * 64 + lane;
      bf16x8 k0r[4], k1r[4], v0r[4], v1r[4];
      #pragma unroll
      for (int i = 0; i < 4; ++i) {
        k0r[i] = pK0[i * 64]; k1r[i] = pK1[i * 64];
        v0r[i] = pV0[i * 64]; v1r[i] = pV1[i * 64];
      }
      #pragma unroll
      for (int ks = 0; ks < 16; ++ks) {
        bf16x8 bk0 = k0r[ks & 3], bk1 = k1r[ks & 3];
        bf16x8 bv0 = v0r[ks & 3], bv1 = v1r[ks & 3];
        if (ks < 12) {
          k0r[ks & 3] = pK0[(ks + 4) * 64]; k1r[ks & 3] = pK1[(ks + 4) * 64];
          v0r[ks & 3] = pV0[(ks + 4) * 64]; v1r[ks & 3] = pV1[(ks + 4) * 64];
        }
        int kc = ks * 32 + g * 8;
        bf16x8 ya0 = ldXY(yb, ar0, kc);
        bf16x8 ya1 = ldXY_c(yb, ar1, kc);
        acck[0][0] = MFMA16(ya0, bk0, acck[0][0]);
        acck[1][0] = MFMA16(ya1, bk0, acck[1][0]);
        acck[0][1] = MFMA16(ya0, bk1, acck[0][1]);
        acck[1][1] = MFMA16(ya1, bk1, acck[1][1]);
        accv[0][0] = MFMA16(ya0, bv0, accv[0][0]);
        accv[1][0] = MFMA16(ya1, bv0, accv[1][0]);
        accv[0][1] = MFMA16(ya0, bv1, accv[0][1]);
        accv[1][1] = MFMA16(ya1, bv1, accv[1][1]);
      }
    }
    // store k (u16 scatter) and vt (packed uint2); rows sub*32..
    #pragma unroll
    for (int mt = 0; mt < 2; ++mt)
      #pragma unroll
      for (int nt = 0; nt < 2; ++nt) {
        #pragma unroll
        for (int r = 0; r < 4; ++r) {
          int row = sub * 32 + mt * 16 + g * 4 + r;
          if (row < 49) {
            unsigned a = ((unsigned)(row * 64 + (nt * 16 + lr) * 2)) ^ SWZ_A(row);
            *(unsigned short*)(kb + a) = f2bf(acck[mt][nt][r]);
          }
        }
        int dh = nt * 16 + lr;
        int t0 = sub * 32 + mt * 16 + g * 4;
        unsigned a = ((unsigned)(dh * 128 + t0 * 2)) ^ SWZ_VT(dh);
        uint2 pk;
        pk.x = pkbf(accv[mt][nt][0], accv[mt][nt][1]);
        pk.y = pkbf(accv[mt][nt][2], accv[mt][nt][3]);
        *(uint2*)(vt + a) = pk;
      }

    __syncthreads();  // q,k,vt visible to both waves of the pair

    // ======== attention (swapped QK^T; one alias-guard barrier) ========
    f32x4 bias[2][4];
    #pragma unroll
    for (int mi = 0; mi < 2; ++mi)
      #pragma unroll
      for (int jt = 0; jt < 4; ++jt)
        bias[mi][jt] = bD[(size_t)(((h * 4 + sub * 2 + mi) * 4 + jt) * 64 + lane)];

    // sim^T = MFMA(A=k, B=q): col = query i (lane&15), regs = key j
    bf16x8 qa[2], kf[4];
    #pragma unroll
    for (int mi = 0; mi < 2; ++mi) qa[mi] = ldQK(qb, sub * 32 + mi * 16 + lr, g * 8);
    #pragma unroll
    for (int jt = 0; jt < 4; ++jt) kf[jt] = ldQK(kb, jt * 16 + lr, g * 8);
    f32x4 accs[2][4];
    #pragma unroll
    for (int mi = 0; mi < 2; ++mi)
      #pragma unroll
      for (int jt = 0; jt < 4; ++jt)
        accs[mi][jt] = MFMA16(kf[jt], qa[mi], fz);

    // in-lane softmax (16 j-values/lane) + 2 shfl across g-replicas; normalize
    uint2 pks[2][4];
    #pragma unroll
    for (int mi = 0; mi < 2; ++mi) {
      f32x4 vals[4];
      #pragma unroll
      for (int jt = 0; jt < 4; ++jt) vals[jt] = accs[mi][jt] + bias[mi][jt];
      float m = vals[0][0];
      #pragma unroll
      for (int jt = 0; jt < 4; ++jt)
        #pragma unroll
        for (int r = 0; r < 4; ++r) m = fmaxf(m, vals[jt][r]);
      m = fmaxf(m, __shfl_xor(m, 16));
      m = fmaxf(m, __shfl_xor(m, 32));
      float s = 0.f;
      #pragma unroll
      for (int jt = 0; jt < 4; ++jt)
        #pragma unroll
        for (int r = 0; r < 4; ++r) {
          float pv = __expf(vals[jt][r] - m);
          vals[jt][r] = pv;
          s += pv;
        }
      s += __shfl_xor(s, 16);
      s += __shfl_xor(s, 32);
      float inv = 1.0f / s;
      #pragma unroll
      for (int jt = 0; jt < 4; ++jt) {
        pks[mi][jt].x = pkbf(vals[jt][0] * inv, vals[jt][1] * inv);
        pks[mi][jt].y = pkbf(vals[jt][2] * inv, vals[jt][3] * inv);
      }
    }

    __syncthreads();  // both waves done reading q/k -> P may overwrite alias

    // P write: packed uint2, own rows, conflict-free
    #pragma unroll
    for (int mi = 0; mi < 2; ++mi) {
      int i = sub * 32 + mi * 16 + lr;
      if (i < 49) {
        #pragma unroll
        for (int jt = 0; jt < 4; ++jt) {
          unsigned a = ((unsigned)(i * 128 + (jt * 16 + g * 4) * 2)) ^ SWZ_P(i);
          *(uint2*)(Pb + a) = pks[mi][jt];
        }
      }
    }

    // PV: out^T[dh][i] = V^T @ P^T ; A = vt rows (pair-shared), B = own P rows
    f32x4 acco[2][2];
    acco[0][0] = fz; acco[0][1] = fz; acco[1][0] = fz; acco[1][1] = fz;
    #pragma unroll
    for (int ks = 0; ks < 2; ++ks) {
      int jc = ks * 32 + g * 8;
      bf16x8 av0 = ldVT(vt, lr, jc);
      bf16x8 av1 = ldVT(vt, lr + 16, jc);
      bf16x8 bp0 = ldP2(Pb, sub * 32 + lr, jc);
      bf16x8 bp1 = ldP2(Pb, sub * 32 + 16 + lr, jc);
      acco[0][0] = MFMA16(av0, bp0, acco[0][0]);
      acco[0][1] = MFMA16(av0, bp1, acco[0][1]);
      acco[1][0] = MFMA16(av1, bp0, acco[1][0]);
      acco[1][1] = MFMA16(av1, bp1, acco[1][1]);
    }

    // store (already normalized): tok = col (lane&15), dh rows f32x4
    float* ow = out + (size_t)bw * 25088 + h * 32;
    #pragma unroll
    for (int it = 0; it < 2; ++it) {
      int tok = sub * 32 + it * 16 + lr;
      if (tok < 49) {
        #pragma unroll
        for (int md = 0; md < 2; ++md)
          *(f32x4*)(&ow[(size_t)tok * 512 + md * 16 + g * 4]) = acco[md][it];
      }
    }
  }
}

extern "C" void kernel_launch(void* const* d_in, const int* in_sizes, int n_in,
                              void* d_out, int out_size, void* d_ws, size_t ws_size,
                              hipStream_t stream) {
  (void)in_sizes; (void)n_in; (void)out_size; (void)ws_size;
  const float* x = (const float*)d_in[0];
  const float* y = (const float*)d_in[1];
  const float* Wq = (const float*)d_in[2];
  const float* Wkv = (const float*)d_in[3];
  const float* bt = (const float*)d_in[4];
  float* out = (float*)d_out;
  char* ws = (char*)d_ws;

  prep_kernel<<<3072, 256, 0, stream>>>(Wq, Wkv, bt, ws);

  (void)hipFuncSetAttribute((const void*)attn_kernel,
                            hipFuncAttributeMaxDynamicSharedMemorySize, 141824);
  attn_kernel<<<4096, 512, 141824, stream>>>(x, y, (const char*)ws,
                                             (const float*)(ws + 1572864), out);
}